// Round 9
// baseline (46.994 us; speedup 1.0000x reference)
//
#include <hip/hip_runtime.h>

// SpatialDeformableTransformer, fused:
//   V = bicubic_resize(flow [8,64,64,2] -> [8,512,512,2])   (jax.image.resize "cubic")
//   x_s = V[...,0] + linspace(-1,1,512)[ox];  y_s = V[...,1] + linspace(-1,1,512)[oy]
//   out = bilinear_sample(U, x_s, y_s) with reference's exact conventions.
//
// Block = 256 threads = one 16x16 output tile.
// Established levers:
//   - separable bicubic (R7: VALUBusy 24->15%, 51.5->46.8 us)
//   - __builtin_nontemporal_store for out (FETCH 190->65 MB). NOTE: asm
//     sc0/sc1 L2-bypass stores are UNSAFE here (harness memset poisons d_out
//     through L2; stale dirty lines evict over our data -> R8 absmax 3.5).
//   - XCD-chunked swizzle (image = bid&7 -> one image per XCD's L2)
// R9 lever: deduplicate per-pixel sampling math. Phase 2 previously redid
// floor/clamp/weights/addressing 4x per pixel (once per chg thread). Now
// phase 1 precomputes per-pixel {int4 corner offsets, float4 weights} into
// LDS; phase 2 is just 2 ds_reads + 4 gathers + 3 vfma + 1 nt store.

#define N_B    8
#define IN_HW  512
#define N_C    16
#define F_HW   64
#define OUTHW  512
#define TILE   16

typedef float fvec4 __attribute__((ext_vector_type(4)));

// Keys cubic kernel, a = -0.5, exactly as jax.image._fill_keys_cubic_kernel
__device__ __forceinline__ float keys_w(float x) {
    if (x >= 2.0f) return 0.0f;
    if (x >= 1.0f) return ((-0.5f * x + 2.5f) * x - 4.0f) * x + 2.0f;
    return ((1.5f * x - 2.5f) * x) * x + 1.0f;
}

// jax compute_weight_mat semantics for 64 -> 512, scale = 8, translation = 0:
//   sample_f = (i + 0.5)/8 - 0.5; taps j = floor(sf)-1 .. +2; out-of-range taps
//   dropped; weights renormalized by the sum of included taps.
__device__ __forceinline__ int cubic_taps(int i, float w[4]) {
    float sf = (i + 0.5f) * 0.125f - 0.5f;
    int jf = (int)floorf(sf);
    float sum = 0.0f;
#pragma unroll
    for (int t = 0; t < 4; ++t) {
        int j = jf - 1 + t;
        float wt = 0.0f;
        if (j >= 0 && j < F_HW) wt = keys_w(fabsf(sf - (float)j));
        w[t] = wt;
        sum += wt;
    }
    float inv = 1.0f / sum;
#pragma unroll
    for (int t = 0; t < 4; ++t) w[t] *= inv;
    return jf - 1;
}

__global__ __launch_bounds__(256, 4) void sdt_kernel(const float* __restrict__ U,
                                                     const float* __restrict__ flow,
                                                     float* __restrict__ out) {
    __shared__ float  wx4[TILE][4];
    __shared__ int    jx0s[TILE];
    __shared__ float  wy4[TILE][4];
    __shared__ int    djy[TILE];          // y-tap base relative to jyB (0..2)
    __shared__ float2 Hs[6][TILE + 1];    // horizontal pass result (+1 pad)
    __shared__ int4   offs4[TILE * TILE]; // per-pixel corner element offsets
    __shared__ float4 wts4[TILE * TILE];  // per-pixel bilinear weights

    const int tid = threadIdx.x;
    // XCD-chunked swizzle: round-robin wg->XCD means bid&7 == XCD id.
    const int b  = blockIdx.x & 7;
    const int t  = blockIdx.x >> 3;          // 0..1023 tile within image
    const int tx = t & 31;
    const int ty = t >> 5;
    const int jyB = 2 * ty - 2;              // closed-form y-tap base for tile

    const float* fb = flow + (size_t)b * (F_HW * F_HW * 2);

    // ---- step A: per-column x-taps (thr 0-15), per-row y-taps (thr 16-31) ----
    if (tid < 16) {
        float w[4];
        const int base = cubic_taps(tx * TILE + tid, w);
        wx4[tid][0] = w[0]; wx4[tid][1] = w[1]; wx4[tid][2] = w[2]; wx4[tid][3] = w[3];
        jx0s[tid] = base;
    } else if (tid < 32) {
        const int py = tid - 16;
        float w[4];
        const int base = cubic_taps(ty * TILE + py, w);
        wy4[py][0] = w[0]; wy4[py][1] = w[1]; wy4[py][2] = w[2]; wy4[py][3] = w[3];
        djy[py] = base - jyB;               // 0..2
    }
    __syncthreads();

    // ---- step B: horizontal pass, 6 flow rows x 16 columns ----
    if (tid < 96) {
        const int jrow = tid >> 4;           // 0..5
        const int col  = tid & 15;
        const int row  = min(max(jyB + jrow, 0), F_HW - 1);
        const float2* frow = (const float2*)fb + row * F_HW;
        const int base = jx0s[col];
        float hx = 0.0f, hy = 0.0f;
#pragma unroll
        for (int r = 0; r < 4; ++r) {
            const int jx = min(max(base + r, 0), F_HW - 1);
            const float w = wx4[col][r];
            const float2 f2 = frow[jx];
            hx = fmaf(w, f2.x, hx);
            hy = fmaf(w, f2.y, hy);
        }
        Hs[jrow][col] = make_float2(hx, hy);
    }
    __syncthreads();

    // ---- step C: vertical pass + grid transform + sampling prep, 1 px/thr ----
    {
        const int px = tid & 15;
        const int py = tid >> 4;
        const int dj = djy[py];
        float vx = 0.0f, vy = 0.0f;
#pragma unroll
        for (int s = 0; s < 4; ++s) {
            const float w = wy4[py][s];
            const float2 h = Hs[dj + s][px];
            vx = fmaf(w, h.x, vx);
            vy = fmaf(w, h.y, vy);
        }
        const int ox = tx * TILE + px;
        const int oy = ty * TILE + py;
        const float xg = -1.0f + (2.0f / 511.0f) * (float)ox;
        const float yg = -1.0f + (2.0f / 511.0f) * (float)oy;
        // reference: x = (xs + 1) * W/2  (NOT (W-1)/2)
        const float x = (vx + xg + 1.0f) * (IN_HW / 2.0f);
        const float y = (vy + yg + 1.0f) * (IN_HW / 2.0f);

        const float fx0 = floorf(x);
        const float fy0 = floorf(y);
        const int x0 = min(max((int)fx0, 0), IN_HW - 1);
        const int x1 = min(max((int)fx0 + 1, 0), IN_HW - 1);
        const int y0 = min(max((int)fy0, 0), IN_HW - 1);
        const int y1 = min(max((int)fy0 + 1, 0), IN_HW - 1);
        // weights from CLIPPED corner coords (replicates reference exactly)
        const float x0f = (float)x0, x1f = (float)x1, y0f = (float)y0, y1f = (float)y1;
        wts4[tid] = make_float4((x1f - x) * (y1f - y),
                                (x1f - x) * (y - y0f),
                                (x - x0f) * (y1f - y),
                                (x - x0f) * (y - y0f));
        offs4[tid] = make_int4((y0 * IN_HW + x0) * N_C,
                               (y1 * IN_HW + x0) * N_C,
                               (y0 * IN_HW + x1) * N_C,
                               (y1 * IN_HW + x1) * N_C);
    }
    __syncthreads();

    // ---- phase 2: 4 passes, 4 threads per pixel; pure load+fma+store ----
    const int chg  = tid & 3;          // channel group (float4)
    const int slot = tid >> 2;         // 0..63
    const float* Ub = U + (size_t)b * (IN_HW * IN_HW * N_C) + chg * 4;
    // out address walked incrementally: passes step 4 rows = 4*512*16 floats
    const int ox0 = tx * TILE + (slot & 15);
    const int oy0 = ty * TILE + (slot >> 4);
    float* outp = out + (((size_t)b * OUTHW + oy0) * OUTHW + ox0) * N_C + chg * 4;

#pragma unroll
    for (int it = 0; it < 4; ++it) {
        const int q = it * 64 + slot;          // pixel within tile
        const int4   o = offs4[q];
        const float4 w = wts4[q];

        const fvec4 a  = *(const fvec4*)(Ub + o.x);
        const fvec4 bb = *(const fvec4*)(Ub + o.y);
        const fvec4 cc = *(const fvec4*)(Ub + o.z);
        const fvec4 dd = *(const fvec4*)(Ub + o.w);
        const fvec4 r = w.x * a + w.y * bb + w.z * cc + w.w * dd;

        __builtin_nontemporal_store(r, (fvec4*)(outp + (size_t)it * 4 * OUTHW * N_C));
    }
}

extern "C" void kernel_launch(void* const* d_in, const int* in_sizes, int n_in,
                              void* d_out, int out_size, void* d_ws, size_t ws_size,
                              hipStream_t stream) {
    const float* U    = (const float*)d_in[0];
    const float* flow = (const float*)d_in[1];
    float* out        = (float*)d_out;
    const int n_blocks = N_B * (OUTHW / TILE) * (OUTHW / TILE);  // 8192
    sdt_kernel<<<dim3(n_blocks), dim3(256), 0, stream>>>(U, flow, out);
}